// Round 13
// baseline (3965.128 us; speedup 1.0000x reference)
//
#include <hip/hip_runtime.h>
#include <hip/hip_fp16.h>

#define B_  64
#define T_  2048
#define I_  64
#define H_  256
#define G4_ 1024   // 4*H

typedef _Float16 f16x8 __attribute__((ext_vector_type(8)));
typedef float    f32x4 __attribute__((ext_vector_type(4)));

__device__ __forceinline__ ushort f2h(float v) {
    return __builtin_bit_cast(ushort, (_Float16)v);
}
__device__ __forceinline__ float h2f(ushort v) {
    return (float)__builtin_bit_cast(_Float16, v);
}

// Raw barrier: orders LDS ops (lgkmcnt) + syncs, but does NOT drain vmcnt --
// lets loop-invariant global weight prefetches survive the barrier (T4).
// sched_barrier(0) fences per guide rule 18.
__device__ __forceinline__ void block_sync_lds() {
    __builtin_amdgcn_sched_barrier(0);
    asm volatile("s_waitcnt lgkmcnt(0)" ::: "memory");
    __builtin_amdgcn_s_barrier();
    __builtin_amdgcn_sched_barrier(0);
}

// ---------------------------------------------------------------------------
// Repack W_hh fp32 [1024][256] -> f16 MFMA A-fragments
//   af[tile=64][kc=8][lane=64][j2=8]
// 16x16x32 A layout: lane l holds A[row = l&15][k = (l>>4)*8 + j2]
// (verified correct end-to-end in rounds 10-12).
// ---------------------------------------------------------------------------
__global__ void repack_kernel(const float* __restrict__ Whh, ushort* __restrict__ af) {
    int o  = blockIdx.x * 256 + threadIdx.x;   // 0 .. 262143 (f16 elements)
    int j2 = o & 7;
    int l  = (o >> 3) & 63;
    int kc = (o >> 9) & 7;
    int tj = o >> 12;
    int row = tj * 16 + (l & 15);
    int col = kc * 32 + (l >> 4) * 8 + j2;
    af[o] = f2h(Whh[row * 256 + col]);
}

// ---------------------------------------------------------------------------
// gx2 = x @ W_ih^T + b_ih + b_hh, TRANSPOSED f16 layout [bt][hd][gate] so the
// lstm kernel fetches one ushort4 per (t,hd).  grid = ((64*TCc)/32, 4).
// ---------------------------------------------------------------------------
__global__ __launch_bounds__(256) void gx_kernel(
    const float* __restrict__ x, const float* __restrict__ Wih,
    const float* __restrict__ bih, const float* __restrict__ bhh,
    ushort* __restrict__ gx2, int t0, int TCc) {

    __shared__ float xs[32][64];
    const int bt0 = blockIdx.x * 32;
    const int gq  = blockIdx.y;                 // gate 0..3 (i,f,g,o)
    const int row = gq * 256 + threadIdx.x;     // W_ih row

    for (int i = threadIdx.x; i < 512; i += 256) {
        int r  = i >> 4, c4 = i & 15;
        int bt = bt0 + r;
        int b  = bt / TCc;
        int tl = bt - b * TCc;
        *(float4*)(&xs[r][c4 * 4]) =
            *(const float4*)(&x[(((size_t)b * T_) + t0 + tl) * I_ + c4 * 4]);
    }
    __syncthreads();

    float w[64];
#pragma unroll
    for (int k = 0; k < 64; ++k) w[k] = Wih[row * I_ + k];
    const float bias = bih[row] + bhh[row];

    for (int i = 0; i < 32; ++i) {
        float acc = bias;
#pragma unroll
        for (int k4 = 0; k4 < 16; ++k4) {
            float4 xq = *(const float4*)(&xs[i][k4 * 4]);
            acc = fmaf(w[k4 * 4 + 0], xq.x, acc);
            acc = fmaf(w[k4 * 4 + 1], xq.y, acc);
            acc = fmaf(w[k4 * 4 + 2], xq.z, acc);
            acc = fmaf(w[k4 * 4 + 3], xq.w, acc);
        }
        gx2[((size_t)(bt0 + i) * 256 + threadIdx.x) * 4 + gq] = f2h(acc);
    }
}

// ---------------------------------------------------------------------------
// Persistent per-batch LSTM, full-MFMA matvec, round-13 CROSS-STEP PREFETCH.
// r12 diagnosis: LDS pipe ~192 b128/step (~2300 cyc) and global ~128KB/step
// (~2000 cyc) poorly overlapped because loads issue <=1 kc ahead and
// __syncthreads drains vmcnt(0) at both barriers.
// Fixes: (1) global kc6/7 frags are LOOP-INVARIANT -- issue before the loop
// and re-issue right after last use each step; their latency hides under
// phase2 + barriers + kc0-5.  (2) raw s_barrier + lgkmcnt(0) only (no vmcnt
// drain) so the prefetch survives the barriers.  (3) aA/aB staggered halves.
// ---------------------------------------------------------------------------
__global__ __launch_bounds__(512, 1)
void lstm_kernel(
    const ushort* __restrict__ af, const ushort* __restrict__ gx2,
    ushort* __restrict__ hbuf,     // [B][TCc][H] f16
    float* __restrict__ state,     // [2][64][256]: c then h
    int TCc, int first) {

    __shared__ __align__(16) ushort sfrag[8 * 8 * 2 * 512]; // kc4,5 frags, 128 KB
    __shared__ __align__(16) ushort hs[2][256];             // h dbuf (f16)
    __shared__ __align__(16) float  gbuf[4][256];           // gate partials, 4 KB

    const int tid = threadIdx.x;
    const int l   = tid & 63;
    const int w   = tid >> 6;
    const int u   = l >> 4;
    const int hd  = tid & 255;
    const int b   = blockIdx.x;
    const bool q0 = (w < 4);

    // --- resident A-frags: kc 0..3 of this wave's 8 tiles (32 x b128, acc) ---
    f16x8 wres[8][4];
#pragma unroll
    for (int j = 0; j < 8; ++j)
#pragma unroll
        for (int kc = 0; kc < 4; ++kc) {
            uint4 v = *(const uint4*)(af + (size_t)(((w * 8 + j) * 8 + kc) * 64 + l) * 8);
            wres[j][kc] = __builtin_bit_cast(f16x8, v);
        }
    // --- LDS A-frags: kc 4,5 -> sfrag[((w*8+j)*2+s)*512 + l*8] ---
#pragma unroll
    for (int j = 0; j < 8; ++j)
#pragma unroll
        for (int s = 0; s < 2; ++s) {
            uint4 v = *(const uint4*)(af + (size_t)(((w * 8 + j) * 8 + 4 + s) * 64 + l) * 8);
            *(uint4*)(sfrag + ((w * 8 + j) * 2 + s) * 512 + l * 8) = v;
        }
    // global-streamed kc 6,7 base: element off = w*32768 + j*4096 + kc*512 + l*8
    const ushort* awl = af + (size_t)w * 32768 + l * 8;
    // LDS read base for this thread's sfrag slice (imm offsets per j,s)
    const ushort* swl = sfrag + w * 8192 + l * 8;

    float c = 0.f, h = 0.f;
    if (q0) {
        if (!first) {
            c = state[b * H_ + hd];
            h = state[B_ * H_ + b * H_ + hd];
        }
        hs[0][hd] = f2h(h);
    }
    __syncthreads();

    const ushort* gxr = gx2 + (size_t)b * TCc * G4_;
    ushort* hb = hbuf + (size_t)b * TCc * H_;

    // ---- prime the loop-invariant global prefetch (kc6,7 of all 8 tiles) ----
    uint4 g6[8], g7[8];
#pragma unroll
    for (int j = 0; j < 8; ++j) g6[j] = *(const uint4*)(awl + j * 4096 + 6 * 512);
#pragma unroll
    for (int j = 0; j < 8; ++j) g7[j] = *(const uint4*)(awl + j * 4096 + 7 * 512);

    for (int tl = 0; tl < TCc; ++tl) {
        const ushort* hsr = hs[tl & 1];
        const int bo = u * 8;               // B-frag per-lane offset

        // gate bias+input term for this step (q0; latency hidden by phase 1)
        ushort4 cg;
        if (q0) cg = *(const ushort4*)(gxr + (size_t)tl * G4_ + hd * 4);

        f32x4 C[8];
#pragma unroll
        for (int j = 0; j < 8; ++j) C[j] = (f32x4){0.f, 0.f, 0.f, 0.f};

        uint4 B0 = *(const uint4*)(hsr + 0 * 32 + bo);
        uint4 B1 = *(const uint4*)(hsr + 1 * 32 + bo);

        // kc0 (resident)
#pragma unroll
        for (int j = 0; j < 8; ++j)
            C[j] = __builtin_amdgcn_mfma_f32_16x16x32_f16(wres[j][0], __builtin_bit_cast(f16x8, B0), C[j], 0, 0, 0);
        uint4 B2 = *(const uint4*)(hsr + 2 * 32 + bo);
        uint4 aA[8];
#pragma unroll
        for (int j = 0; j < 4; ++j) aA[j] = *(const uint4*)(swl + (j * 2 + 0) * 512);  // kc4 lo

        // kc1
#pragma unroll
        for (int j = 0; j < 8; ++j)
            C[j] = __builtin_amdgcn_mfma_f32_16x16x32_f16(wres[j][1], __builtin_bit_cast(f16x8, B1), C[j], 0, 0, 0);
        uint4 B3 = *(const uint4*)(hsr + 3 * 32 + bo);
#pragma unroll
        for (int j = 4; j < 8; ++j) aA[j] = *(const uint4*)(swl + (j * 2 + 0) * 512);  // kc4 hi

        // kc2
#pragma unroll
        for (int j = 0; j < 8; ++j)
            C[j] = __builtin_amdgcn_mfma_f32_16x16x32_f16(wres[j][2], __builtin_bit_cast(f16x8, B2), C[j], 0, 0, 0);
        uint4 B4 = *(const uint4*)(hsr + 4 * 32 + bo);
        uint4 aB[8];
#pragma unroll
        for (int j = 0; j < 4; ++j) aB[j] = *(const uint4*)(swl + (j * 2 + 1) * 512);  // kc5 lo

        // kc3
#pragma unroll
        for (int j = 0; j < 8; ++j)
            C[j] = __builtin_amdgcn_mfma_f32_16x16x32_f16(wres[j][3], __builtin_bit_cast(f16x8, B3), C[j], 0, 0, 0);
        uint4 B5 = *(const uint4*)(hsr + 5 * 32 + bo);
#pragma unroll
        for (int j = 4; j < 8; ++j) aB[j] = *(const uint4*)(swl + (j * 2 + 1) * 512);  // kc5 hi

        // kc4 (LDS)
#pragma unroll
        for (int j = 0; j < 8; ++j)
            C[j] = __builtin_amdgcn_mfma_f32_16x16x32_f16(__builtin_bit_cast(f16x8, aA[j]), __builtin_bit_cast(f16x8, B4), C[j], 0, 0, 0);
        uint4 B6 = *(const uint4*)(hsr + 6 * 32 + bo);

        // kc5 (LDS)
#pragma unroll
        for (int j = 0; j < 8; ++j)
            C[j] = __builtin_amdgcn_mfma_f32_16x16x32_f16(__builtin_bit_cast(f16x8, aB[j]), __builtin_bit_cast(f16x8, B5), C[j], 0, 0, 0);
        uint4 B7 = *(const uint4*)(hsr + 7 * 32 + bo);

        // kc6 (global, prefetched >1 step ago -- latency fully hidden)
#pragma unroll
        for (int j = 0; j < 8; ++j)
            C[j] = __builtin_amdgcn_mfma_f32_16x16x32_f16(__builtin_bit_cast(f16x8, g6[j]), __builtin_bit_cast(f16x8, B6), C[j], 0, 0, 0);
        // kc7 (global)
#pragma unroll
        for (int j = 0; j < 8; ++j)
            C[j] = __builtin_amdgcn_mfma_f32_16x16x32_f16(__builtin_bit_cast(f16x8, g7[j]), __builtin_bit_cast(f16x8, B7), C[j], 0, 0, 0);

        // re-issue the loop-invariant prefetch for the NEXT step; these stay
        // in flight across both raw barriers (no vmcnt drain)
#pragma unroll
        for (int j = 0; j < 8; ++j) g6[j] = *(const uint4*)(awl + j * 4096 + 6 * 512);
#pragma unroll
        for (int j = 0; j < 8; ++j) g7[j] = *(const uint4*)(awl + j * 4096 + 7 * 512);

        // C col 0 -> gbuf (lanes l&15==0 hold rows 4u..4u+3 in 4 regs)
        if ((l & 15) == 0) {
            const int lr = u * 4;
#pragma unroll
            for (int j = 0; j < 8; ++j) {
                const int tj = w * 8 + j;
                *(f32x4*)(&gbuf[tj >> 4][(tj & 15) * 16 + lr]) = C[j];
            }
        }
        block_sync_lds();

        // ---------------- phase 2: elementwise (waves 0-3) ------------------
        if (q0) {
            float ai  = gbuf[0][hd] + h2f(cg.x);
            float afv = gbuf[1][hd] + h2f(cg.y);
            float ag  = gbuf[2][hd] + h2f(cg.z);
            float ao  = gbuf[3][hd] + h2f(cg.w);

            float si = __builtin_amdgcn_rcpf(1.f + __expf(-ai));
            float sf = __builtin_amdgcn_rcpf(1.f + __expf(-afv));
            float so = __builtin_amdgcn_rcpf(1.f + __expf(-ao));
            float eg = __expf(2.f * ag);
            float tg = (eg - 1.f) * __builtin_amdgcn_rcpf(eg + 1.f);
            c = sf * c + si * tg;
            float ec = __expf(2.f * c);
            float tc = (ec - 1.f) * __builtin_amdgcn_rcpf(ec + 1.f);
            h = so * tc;

            ushort hh = f2h(h);
            hs[(tl + 1) & 1][hd] = hh;
            hb[(size_t)tl * H_ + hd] = hh;
        }
        block_sync_lds();
    }

    if (q0) {
        state[b * H_ + hd]           = c;
        state[B_ * H_ + b * H_ + hd] = h;
    }
}

// ---------------------------------------------------------------------------
// out[b,t] = sum_hd h[b,t,hd] * Wo[hd] + bo.  h f16 rows, fully dense reads.
// ---------------------------------------------------------------------------
__global__ __launch_bounds__(256) void proj_kernel(
    const ushort* __restrict__ hbuf, const float* __restrict__ Wo,
    const float* __restrict__ bo, float* __restrict__ out, int t0, int TCc) {

    const int lane = threadIdx.x & 63;
    const int wid  = blockIdx.x * 4 + (threadIdx.x >> 6);
    const int nw   = gridDim.x * 4;
    const int rows = B_ * TCc;

    float4 w = *(const float4*)(Wo + lane * 4);
    const float bov = bo[0];

    for (int r = wid; r < rows; r += nw) {
        const ushort* hp = hbuf + (size_t)r * H_ + lane * 4;
        ushort4 u = *(const ushort4*)hp;
        float p = h2f(u.x) * w.x + h2f(u.y) * w.y + h2f(u.z) * w.z + h2f(u.w) * w.w;
#pragma unroll
        for (int m = 1; m < 64; m <<= 1) p += __shfl_xor(p, m, 64);
        if (lane == 0) {
            int b  = r / TCc;
            int tl = r - b * TCc;
            out[(size_t)b * T_ + t0 + tl] = p + bov;
        }
    }
}

// ---------------------------------------------------------------------------
extern "C" void kernel_launch(void* const* d_in, const int* in_sizes, int n_in,
                              void* d_out, int out_size, void* d_ws, size_t ws_size,
                              hipStream_t stream) {
    const float* x   = (const float*)d_in[0];
    const float* Wih = (const float*)d_in[1];
    const float* Whh = (const float*)d_in[2];
    const float* bih = (const float*)d_in[3];
    const float* bhh = (const float*)d_in[4];
    const float* Wo  = (const float*)d_in[5];
    const float* bo  = (const float*)d_in[6];
    float* out = (float*)d_out;

    char* ws = (char*)d_ws;
    ushort* af    = (ushort*)ws;                              // 512 KB A-frags
    float*  state = (float*)(ws + 512 * 1024);                // 128 KB
    char*   dyn   = ws + 640 * 1024;                          // gx2 + hbuf chunks

    size_t avail = (ws_size > 640 * 1024) ? ws_size - 640 * 1024 : 0;
    // per (b,t): gx2 row 2048 B + hbuf row 512 B
    long long tcmax = (long long)(avail / ((size_t)B_ * (G4_ + H_) * 2));
    // Cap chunks at 512 steps so gx2 (64MB) + hbuf (16MB) stay L3-resident.
    int TC = (tcmax > 512) ? 512 : (int)tcmax;
    TC &= ~63;               // multiple of 64
    if (TC < 64) TC = 64;    // minimum viable chunk

    repack_kernel<<<1024, 256, 0, stream>>>(Whh, af);

    for (int t0 = 0; t0 < T_; t0 += TC) {
        int TCc = (T_ - t0 < TC) ? (T_ - t0) : TC;
        ushort* gxb  = (ushort*)dyn;
        ushort* hbuf = (ushort*)(dyn + (size_t)B_ * TCc * G4_ * 2);
        dim3 g1((B_ * TCc) / 32, 4);
        gx_kernel<<<g1, 256, 0, stream>>>(x, Wih, bih, bhh, gxb, t0, TCc);
        lstm_kernel<<<B_, 512, 0, stream>>>(af, gxb, hbuf, state, TCc, t0 == 0 ? 1 : 0);
        proj_kernel<<<256, 256, 0, stream>>>(hbuf, Wo, bo, out, t0, TCc);
    }
    (void)in_sizes; (void)n_in; (void)out_size;
}

// Round 14
// 3123.262 us; speedup vs baseline: 1.2695x; 1.2695x over previous
//
#include <hip/hip_runtime.h>
#include <hip/hip_fp16.h>

#define B_  64
#define T_  2048
#define I_  64
#define H_  256
#define G4_ 1024   // 4*H

typedef _Float16 h2v __attribute__((ext_vector_type(2)));

__device__ __forceinline__ float fdot2(uint32_t a, uint32_t b, float c) {
#if __has_builtin(__builtin_amdgcn_fdot2)
    return __builtin_amdgcn_fdot2(__builtin_bit_cast(h2v, a), __builtin_bit_cast(h2v, b), c, false);
#else
    h2v ha = __builtin_bit_cast(h2v, a), hb = __builtin_bit_cast(h2v, b);
    return c + (float)ha.x * (float)hb.x + (float)ha.y * (float)hb.y;
#endif
}

__device__ __forceinline__ ushort f2h(float v) {
    return __builtin_bit_cast(ushort, (_Float16)v);
}
__device__ __forceinline__ float h2f(ushort v) {
    return (float)__builtin_bit_cast(_Float16, v);
}

// ---------------------------------------------------------------------------
// Repack W_hh fp32 [1024][256] -> f16 wpk[g][kc][h][j]  (g=gate, kc=K/8 chunk,
// h=hdim 0..255, j=0..7).  Coalesced 16B/lane preload in the LSTM kernel.
// (r8 layout -- proven.)
// ---------------------------------------------------------------------------
__global__ void repack_kernel(const float* __restrict__ Whh, ushort* __restrict__ wpk) {
    int o  = blockIdx.x * 256 + threadIdx.x;   // 0 .. 262143
    int j  = o & 7;
    int h  = (o >> 3) & 255;
    int kc = (o >> 11) & 31;
    int g  = o >> 16;
    float v = Whh[(g * 256 + h) * 256 + kc * 8 + j];
    wpk[o] = f2h(v);
}

// ---------------------------------------------------------------------------
// gx2 = x @ W_ih^T + b_ih + b_hh, TRANSPOSED f16 layout [bt][hd][gate].
// Round-14: packed-f16 fdot2 inner loop (f32 accumulate) -- halves the VALU
// issue vs the fp32 fmaf version (1024 fdot2 vs 2048 fmaf per thread).
// grid = ((64*TCc)/32, 4), block = 256.
// ---------------------------------------------------------------------------
__global__ __launch_bounds__(256) void gx_kernel(
    const float* __restrict__ x, const float* __restrict__ Wih,
    const float* __restrict__ bih, const float* __restrict__ bhh,
    ushort* __restrict__ gx2, int t0, int TCc) {

    __shared__ uint32_t xsp[32][32];            // 32 bt-rows x 32 f16-pairs
    const int bt0 = blockIdx.x * 32;
    const int gq  = blockIdx.y;                 // gate 0..3 (i,f,g,o)
    const int row = gq * 256 + threadIdx.x;     // W_ih row

    for (int i = threadIdx.x; i < 512; i += 256) {
        int r  = i >> 4, c4 = i & 15;
        int bt = bt0 + r;
        int b  = bt / TCc;
        int tl = bt - b * TCc;
        float4 v = *(const float4*)(&x[(((size_t)b * T_) + t0 + tl) * I_ + c4 * 4]);
        xsp[r][c4 * 2 + 0] = (uint32_t)f2h(v.x) | ((uint32_t)f2h(v.y) << 16);
        xsp[r][c4 * 2 + 1] = (uint32_t)f2h(v.z) | ((uint32_t)f2h(v.w) << 16);
    }
    __syncthreads();

    uint32_t wp[32];
#pragma unroll
    for (int k = 0; k < 32; ++k) {
        float a = Wih[row * I_ + 2 * k];
        float b = Wih[row * I_ + 2 * k + 1];
        wp[k] = (uint32_t)f2h(a) | ((uint32_t)f2h(b) << 16);
    }
    const float bias = bih[row] + bhh[row];

    for (int i = 0; i < 32; ++i) {
        float acc = bias;
#pragma unroll
        for (int k4 = 0; k4 < 8; ++k4) {
            uint4 xq = *(const uint4*)(&xsp[i][k4 * 4]);   // wave-uniform bcast
            acc = fdot2(wp[k4 * 4 + 0], xq.x, acc);
            acc = fdot2(wp[k4 * 4 + 1], xq.y, acc);
            acc = fdot2(wp[k4 * 4 + 2], xq.z, acc);
            acc = fdot2(wp[k4 * 4 + 3], xq.w, acc);
        }
        gx2[((size_t)(bt0 + i) * 256 + threadIdx.x) * 4 + gq] = f2h(acc);
    }
}

// ---------------------------------------------------------------------------
// Persistent per-batch LSTM -- EXACT round-8 champion structure (725 us/chunk
// measured; the fdot2 design beat 4 rounds of MFMA variants at ~890).
// 64 blocks x 512 threads, LB(512,1).  Thread pair (hd, hd+256) splits K=256
// (q = tid>>8).  Regs: i/f/g half-rows (192 dw) + last 2 kc of o (8 dw).
// LDS: o-gate kc 0..13 per half, [kc'][q][hd][8] 1KB-contiguous wave reads
// (0 conflicts).  q=1 hands partials to q=0 via packed float4.  2 barriers.
// Only change vs r8: hbuf is full-T (proj runs once at the end).
// ---------------------------------------------------------------------------
__global__ __launch_bounds__(512, 1)
void lstm_kernel(
    const ushort* __restrict__ wpk, const ushort* __restrict__ gx2,
    ushort* __restrict__ hbuf,     // [B][T][H] f16 (full-T)
    float* __restrict__ state,     // [2][64][256]: c then h
    int TCc, int t0, int first) {

    __shared__ __align__(16) ushort wg4[14 * 2 * 256 * 8]; // o-gate stream, 112 KB
    __shared__ __align__(16) ushort hs[256];               // h(t-1) as f16
    __shared__ __align__(16) float pex[256][4];            // q=1 -> q=0 partials

    const int tid   = threadIdx.x;
    const int hd    = tid & 255;       // owned h-dim
    const int q     = tid >> 8;        // K-half: 0 -> kc 0..15, 1 -> kc 16..31
    const int kbase = q << 4;
    const int b     = blockIdx.x;
    const bool q0   = (q == 0);

    // --- preload i/f/g gate half-rows into registers (16B/lane, coalesced) ---
    uint32_t wi[64], wf[64], wg[64];
#pragma unroll
    for (int k = 0; k < 16; ++k) {
        uint4 v = *(const uint4*)(wpk + (size_t)(0 * 32 + kbase + k) * 2048 + hd * 8);
        wi[k * 4 + 0] = v.x; wi[k * 4 + 1] = v.y; wi[k * 4 + 2] = v.z; wi[k * 4 + 3] = v.w;
    }
#pragma unroll
    for (int k = 0; k < 16; ++k) {
        uint4 v = *(const uint4*)(wpk + (size_t)(1 * 32 + kbase + k) * 2048 + hd * 8);
        wf[k * 4 + 0] = v.x; wf[k * 4 + 1] = v.y; wf[k * 4 + 2] = v.z; wf[k * 4 + 3] = v.w;
    }
#pragma unroll
    for (int k = 0; k < 16; ++k) {
        uint4 v = *(const uint4*)(wpk + (size_t)(2 * 32 + kbase + k) * 2048 + hd * 8);
        wg[k * 4 + 0] = v.x; wg[k * 4 + 1] = v.y; wg[k * 4 + 2] = v.z; wg[k * 4 + 3] = v.w;
    }
    // --- o-gate: kc 0..13 -> LDS [kc'][q][hd][8]; kc 14..15 -> registers ---
#pragma unroll
    for (int k = 0; k < 14; ++k) {
        uint4 v = *(const uint4*)(wpk + (size_t)(3 * 32 + kbase + k) * 2048 + hd * 8);
        *(uint4*)(wg4 + ((k * 2 + q) * 256 + hd) * 8) = v;
    }
    uint32_t wo_r[8];
#pragma unroll
    for (int k = 0; k < 2; ++k) {
        uint4 v = *(const uint4*)(wpk + (size_t)(3 * 32 + kbase + 14 + k) * 2048 + hd * 8);
        wo_r[k * 4 + 0] = v.x; wo_r[k * 4 + 1] = v.y; wo_r[k * 4 + 2] = v.z; wo_r[k * 4 + 3] = v.w;
    }

    float c = 0.f, h = 0.f;
    if (q0) {
        if (!first) {
            c = state[b * H_ + hd];
            h = state[B_ * H_ + b * H_ + hd];
        }
        hs[hd] = f2h(h);
    }
    __syncthreads();

    const ushort* gxb = gx2 + (size_t)b * TCc * G4_;
    ushort* hb = hbuf + (size_t)b * T_ * H_ + (size_t)t0 * H_;

    ushort4 cg;
    if (q0) cg = *(const ushort4*)(gxb + (size_t)0 * G4_ + hd * 4);

    for (int tl = 0; tl < TCc; ++tl) {
        // prefetch next step's gates (q0 only; hidden under the dot loop)
        ushort4 ng;
        if (q0) {
            const int tn = (tl + 1 < TCc) ? tl + 1 : tl;
            ng = *(const ushort4*)(gxb + (size_t)tn * G4_ + hd * 4);
        }

        float ai = 0.f, af = 0.f, agv = 0.f, ao = 0.f;

        // --- kc 0..13 of this half: o-weights stream from LDS ---
#pragma unroll
        for (int k = 0; k < 14; ++k) {
            const int kc = kbase + k;
            uint4 hq = *(const uint4*)(hs + kc * 8);                        // bcast
            uint4 wo = *(const uint4*)(wg4 + ((k * 2 + q) * 256 + hd) * 8); // stream
            ai  = fdot2(wi[k * 4 + 0], hq.x, ai);
            ai  = fdot2(wi[k * 4 + 1], hq.y, ai);
            ai  = fdot2(wi[k * 4 + 2], hq.z, ai);
            ai  = fdot2(wi[k * 4 + 3], hq.w, ai);
            af  = fdot2(wf[k * 4 + 0], hq.x, af);
            af  = fdot2(wf[k * 4 + 1], hq.y, af);
            af  = fdot2(wf[k * 4 + 2], hq.z, af);
            af  = fdot2(wf[k * 4 + 3], hq.w, af);
            agv = fdot2(wg[k * 4 + 0], hq.x, agv);
            agv = fdot2(wg[k * 4 + 1], hq.y, agv);
            agv = fdot2(wg[k * 4 + 2], hq.z, agv);
            agv = fdot2(wg[k * 4 + 3], hq.w, agv);
            ao  = fdot2(wo.x, hq.x, ao);
            ao  = fdot2(wo.y, hq.y, ao);
            ao  = fdot2(wo.z, hq.z, ao);
            ao  = fdot2(wo.w, hq.w, ao);
        }
        // --- kc 14..15 of this half: o-weights from registers ---
#pragma unroll
        for (int k = 14; k < 16; ++k) {
            const int kc = kbase + k;
            const int r  = (k - 14) * 4;
            uint4 hq = *(const uint4*)(hs + kc * 8);
            ai  = fdot2(wi[k * 4 + 0], hq.x, ai);
            ai  = fdot2(wi[k * 4 + 1], hq.y, ai);
            ai  = fdot2(wi[k * 4 + 2], hq.z, ai);
            ai  = fdot2(wi[k * 4 + 3], hq.w, ai);
            af  = fdot2(wf[k * 4 + 0], hq.x, af);
            af  = fdot2(wf[k * 4 + 1], hq.y, af);
            af  = fdot2(wf[k * 4 + 2], hq.z, af);
            af  = fdot2(wf[k * 4 + 3], hq.w, af);
            agv = fdot2(wg[k * 4 + 0], hq.x, agv);
            agv = fdot2(wg[k * 4 + 1], hq.y, agv);
            agv = fdot2(wg[k * 4 + 2], hq.z, agv);
            agv = fdot2(wg[k * 4 + 3], hq.w, agv);
            ao  = fdot2(wo_r[r + 0], hq.x, ao);
            ao  = fdot2(wo_r[r + 1], hq.y, ao);
            ao  = fdot2(wo_r[r + 2], hq.z, ao);
            ao  = fdot2(wo_r[r + 3], hq.w, ao);
        }

        if (!q0) {
            float4 p; p.x = ai; p.y = af; p.z = agv; p.w = ao;
            *(float4*)(&pex[hd][0]) = p;
        }
        __syncthreads();

        if (q0) {
            float4 px = *(const float4*)(&pex[hd][0]);
            ai += px.x; af += px.y; agv += px.z; ao += px.w;

            ai += h2f(cg.x); af += h2f(cg.y); agv += h2f(cg.z); ao += h2f(cg.w);

            float si = __builtin_amdgcn_rcpf(1.f + __expf(-ai));
            float sf = __builtin_amdgcn_rcpf(1.f + __expf(-af));
            float so = __builtin_amdgcn_rcpf(1.f + __expf(-ao));
            float eg = __expf(2.f * agv);
            float tg = (eg - 1.f) * __builtin_amdgcn_rcpf(eg + 1.f);
            c = sf * c + si * tg;
            float ec = __expf(2.f * c);
            float tc = (ec - 1.f) * __builtin_amdgcn_rcpf(ec + 1.f);
            h = so * tc;

            ushort hh = f2h(h);
            hs[hd] = hh;
            hb[(size_t)tl * H_ + hd] = hh;
            cg = ng;
        }
        __syncthreads();
    }

    if (q0) {
        state[b * H_ + hd]           = c;
        state[B_ * H_ + b * H_ + hd] = h;
    }
}

// ---------------------------------------------------------------------------
// out[b,t] = sum_hd h[b,t,hd] * Wo[hd] + bo.  Single launch over full T.
// hbuf row r = b*T + t maps directly to out[r].
// ---------------------------------------------------------------------------
__global__ __launch_bounds__(256) void proj_kernel(
    const ushort* __restrict__ hbuf, const float* __restrict__ Wo,
    const float* __restrict__ bo, float* __restrict__ out) {

    const int lane = threadIdx.x & 63;
    const int wid  = blockIdx.x * 4 + (threadIdx.x >> 6);
    const int nw   = gridDim.x * 4;
    const int rows = B_ * T_;

    float4 w = *(const float4*)(Wo + lane * 4);
    const float bov = bo[0];

    for (int r = wid; r < rows; r += nw) {
        const ushort* hp = hbuf + (size_t)r * H_ + lane * 4;
        ushort4 u = *(const ushort4*)hp;
        float p = h2f(u.x) * w.x + h2f(u.y) * w.y + h2f(u.z) * w.z + h2f(u.w) * w.w;
#pragma unroll
        for (int m = 1; m < 64; m <<= 1) p += __shfl_xor(p, m, 64);
        if (lane == 0) out[r] = p + bov;
    }
}

// ---------------------------------------------------------------------------
extern "C" void kernel_launch(void* const* d_in, const int* in_sizes, int n_in,
                              void* d_out, int out_size, void* d_ws, size_t ws_size,
                              hipStream_t stream) {
    const float* x   = (const float*)d_in[0];
    const float* Wih = (const float*)d_in[1];
    const float* Whh = (const float*)d_in[2];
    const float* bih = (const float*)d_in[3];
    const float* bhh = (const float*)d_in[4];
    const float* Wo  = (const float*)d_in[5];
    const float* bo  = (const float*)d_in[6];
    float* out = (float*)d_out;

    char* ws = (char*)d_ws;
    ushort* wpk   = (ushort*)ws;                              // 512 KB
    float*  state = (float*)(ws + 512 * 1024);                // 128 KB
    ushort* hbuf  = (ushort*)(ws + 640 * 1024);               // 64 MB full-T h
    const size_t hbuf_bytes = (size_t)B_ * T_ * H_ * 2;
    char*   dyn   = ws + 640 * 1024 + hbuf_bytes;             // gx2 chunks

    size_t fixed = 640 * 1024 + hbuf_bytes;
    size_t avail = (ws_size > fixed) ? ws_size - fixed : 0;
    long long tcmax = (long long)(avail / ((size_t)B_ * G4_ * 2));
    // Cap chunks at 512 steps so gx2 (64MB) + hbuf stay L3-resident (r3/r4).
    int TC = (tcmax > 512) ? 512 : (int)tcmax;
    TC &= ~63;               // multiple of 64
    if (TC < 64) TC = 64;    // minimum viable chunk

    repack_kernel<<<1024, 256, 0, stream>>>(Whh, wpk);

    for (int t0 = 0; t0 < T_; t0 += TC) {
        int TCc = (T_ - t0 < TC) ? (T_ - t0) : TC;
        ushort* gxb = (ushort*)dyn;
        dim3 g1((B_ * TCc) / 32, 4);
        gx_kernel<<<g1, 256, 0, stream>>>(x, Wih, bih, bhh, gxb, t0, TCc);
        lstm_kernel<<<B_, 512, 0, stream>>>(wpk, gxb, hbuf, state, TCc, t0, t0 == 0 ? 1 : 0);
    }
    proj_kernel<<<512, 256, 0, stream>>>(hbuf, Wo, bo, out);
    (void)in_sizes; (void)n_in; (void)out_size;
}